// Round 1
// baseline (358.027 us; speedup 1.0000x reference)
//
#include <hip/hip_runtime.h>
#include <math.h>

#define NBATCH 8
#define SEQL   2048
#define NHEAD  16
#define DDIM   64
#define CHK    64
#define NCHUNK (SEQL / CHK)
#define MH     32
#define NTHREADS 512
#define EPSV   1e-6f

__device__ __forceinline__ float phi(float x) {
    // elu(x) + 1
    return x > 0.0f ? x + 1.0f : __expf(x);
}

__global__ __launch_bounds__(NTHREADS)
void linattn_fused(const float* __restrict__ qg,
                   const float* __restrict__ kg,
                   const float* __restrict__ vg,
                   float* __restrict__ og) {
    const int bid   = blockIdx.x;      // [0, 256)
    const int mhalf = bid & 1;         // which half of m
    const int nh    = bid >> 1;        // n*16 + h
    const int n     = nh >> 4;
    const int hh    = nh & 15;
    const int tid   = threadIdx.x;

    // LDS (pad row stride to 68 floats = 272B, 16B-aligned, bank-spreading)
    __shared__ float sQ[64][68];    // phi(Q) chunk, row-major [t][d]
    __shared__ float sK[64][68];    // phi(K) chunk, row-major [s][d]
    __shared__ float sP[64][68];    // masked scores [t][s]
    __shared__ float sVt[32][68];   // V chunk transposed [c][s]
    __shared__ float sSt[32][68];   // state transposed  [c][d] (persistent)
    __shared__ float sKsum[64];     // running k-sum over previous chunks
    __shared__ float sZq[64][2];    // q . ksum_prev partials
    __shared__ float sZ[64];        // final normalizer per row

    const size_t tstride = (size_t)NHEAD * DDIM;            // 1024 floats / timestep
    const size_t base0   = ((size_t)n * SEQL * NHEAD + hh) * DDIM;
    const float* qb = qg + base0;
    const float* kb = kg + base0;
    const float* vb = vg + base0 + mhalf * MH;
    float*       ob = og + base0 + mhalf * MH;

    // zero persistent state
    for (int i = tid; i < 32 * 68; i += NTHREADS) (&sSt[0][0])[i] = 0.0f;
    if (tid < 64) sKsum[tid] = 0.0f;
    __syncthreads();

    float accB[4][4];   // state-delta accumulator (waves 4-5)
    float accO[4][4];   // output accumulator       (waves 0-1)

    for (int tc = 0; tc < NCHUNK; ++tc) {
        const int t0 = tc * CHK;

        // ---------------- load chunk: Q,K (phi) row-major; V transposed ----
        #pragma unroll
        for (int i = 0; i < 2; ++i) {
            const int f   = tid + i * NTHREADS;    // [0,1024) float4 index
            const int row = f >> 4;
            const int c4  = (f & 15) << 2;
            const float4 qv = *(const float4*)(qb + (size_t)(t0 + row) * tstride + c4);
            float4 qp; qp.x = phi(qv.x); qp.y = phi(qv.y); qp.z = phi(qv.z); qp.w = phi(qv.w);
            *(float4*)&sQ[row][c4] = qp;
            const float4 kv = *(const float4*)(kb + (size_t)(t0 + row) * tstride + c4);
            float4 kp; kp.x = phi(kv.x); kp.y = phi(kv.y); kp.z = phi(kv.z); kp.w = phi(kv.w);
            *(float4*)&sK[row][c4] = kp;
        }
        {
            const int f   = tid;                   // [0,512) float4 index
            const int row = f >> 3;
            const int c4  = (f & 7) << 2;
            const float4 vv = *(const float4*)(vb + (size_t)(t0 + row) * tstride + c4);
            sVt[c4 + 0][row] = vv.x;
            sVt[c4 + 1][row] = vv.y;
            sVt[c4 + 2][row] = vv.z;
            sVt[c4 + 3][row] = vv.w;
        }
        __syncthreads();

        // ---------------- phase X -----------------------------------------
        if (tid < 256) {
            // waves 0-3: P = phiQ . phiK^T  (4x4 tile per thread), causal mask
            const int r0 = (tid >> 4) << 2;
            const int c0 = (tid & 15) << 2;
            float acc[4][4] = {};
            for (int dd = 0; dd < 64; dd += 4) {
                float4 qa[4], kk[4];
                #pragma unroll
                for (int i = 0; i < 4; ++i) qa[i] = *(const float4*)&sQ[r0 + i][dd];
                #pragma unroll
                for (int j = 0; j < 4; ++j) kk[j] = *(const float4*)&sK[c0 + j][dd];
                #pragma unroll
                for (int i = 0; i < 4; ++i)
                    #pragma unroll
                    for (int j = 0; j < 4; ++j)
                        acc[i][j] += qa[i].x * kk[j].x + qa[i].y * kk[j].y
                                   + qa[i].z * kk[j].z + qa[i].w * kk[j].w;
            }
            #pragma unroll
            for (int i = 0; i < 4; ++i) {
                float4 m;
                m.x = (c0 + 0 <= r0 + i) ? acc[i][0] : 0.0f;
                m.y = (c0 + 1 <= r0 + i) ? acc[i][1] : 0.0f;
                m.z = (c0 + 2 <= r0 + i) ? acc[i][2] : 0.0f;
                m.w = (c0 + 3 <= r0 + i) ? acc[i][3] : 0.0f;
                *(float4*)&sP[r0 + i][c0] = m;
            }
        } else if (tid < 384) {
            // waves 4-5: state delta dSt[c][d] = sum_s Vt[c][s] * K[s][d]
            const int u  = tid - 256;
            const int c0 = (u >> 4) << 2;
            const int d0 = (u & 15) << 2;
            #pragma unroll
            for (int i = 0; i < 4; ++i)
                #pragma unroll
                for (int j = 0; j < 4; ++j) accB[i][j] = 0.0f;
            for (int s = 0; s < 64; ++s) {
                const float4 kk = *(const float4*)&sK[s][d0];
                #pragma unroll
                for (int i = 0; i < 4; ++i) {
                    const float va = sVt[c0 + i][s];
                    accB[i][0] += va * kk.x;
                    accB[i][1] += va * kk.y;
                    accB[i][2] += va * kk.z;
                    accB[i][3] += va * kk.w;
                }
            }
        } else {
            // waves 6-7: zq[r] = q_r . ksum_prev (two halves of d)
            const int u  = tid - 384;       // [0,128)
            const int r  = u >> 1;
            const int hf = u & 1;
            const int d0 = hf << 5;
            float zp = 0.0f;
            for (int d = 0; d < 32; ++d) zp += sQ[r][d0 + d] * sKsum[d0 + d];
            sZq[r][hf] = zp;
        }
        __syncthreads();

        // ---------------- phase Y -----------------------------------------
        if (tid < 128) {
            // waves 0-1: out = Q.S_old + P.V  (4x4 tile over [64 x 32])
            const int r0 = (tid >> 3) << 2;
            const int c0 = (tid & 7) << 2;
            #pragma unroll
            for (int i = 0; i < 4; ++i)
                #pragma unroll
                for (int j = 0; j < 4; ++j) accO[i][j] = 0.0f;
            // inter-chunk: Q . S_old   (S stored transposed -> inner d contiguous)
            for (int dd = 0; dd < 64; dd += 4) {
                float4 qa[4], sb[4];
                #pragma unroll
                for (int i = 0; i < 4; ++i) qa[i] = *(const float4*)&sQ[r0 + i][dd];
                #pragma unroll
                for (int j = 0; j < 4; ++j) sb[j] = *(const float4*)&sSt[c0 + j][dd];
                #pragma unroll
                for (int i = 0; i < 4; ++i)
                    #pragma unroll
                    for (int j = 0; j < 4; ++j)
                        accO[i][j] += qa[i].x * sb[j].x + qa[i].y * sb[j].y
                                    + qa[i].z * sb[j].z + qa[i].w * sb[j].w;
            }
            // intra-chunk: P . V   (V stored transposed -> inner s contiguous)
            for (int ss = 0; ss < 64; ss += 4) {
                float4 pa[4], vv[4];
                #pragma unroll
                for (int i = 0; i < 4; ++i) pa[i] = *(const float4*)&sP[r0 + i][ss];
                #pragma unroll
                for (int j = 0; j < 4; ++j) vv[j] = *(const float4*)&sVt[c0 + j][ss];
                #pragma unroll
                for (int i = 0; i < 4; ++i)
                    #pragma unroll
                    for (int j = 0; j < 4; ++j)
                        accO[i][j] += pa[i].x * vv[j].x + pa[i].y * vv[j].y
                                    + pa[i].z * vv[j].z + pa[i].w * vv[j].w;
            }
        } else if (tid < 192) {
            // wave 2: z[r] = rowsum(masked P) + zq + eps
            const int r = tid - 128;
            float zs = 0.0f;
            for (int s = 0; s < 64; ++s) zs += sP[r][s];
            sZ[r] = zs + sZq[r][0] + sZq[r][1] + EPSV;
        } else if (tid < 256) {
            // wave 3: ksum[d] += column-sum of K chunk
            const int d = tid - 192;
            float kd = 0.0f;
            for (int s = 0; s < 64; ++s) kd += sK[s][d];
            sKsum[d] += kd;
        }
        __syncthreads();

        // ---------------- phase Z -----------------------------------------
        if (tid < 128) {
            // waves 0-1: divide by z and store
            const int r0 = (tid >> 3) << 2;
            const int c0 = (tid & 7) << 2;
            #pragma unroll
            for (int i = 0; i < 4; ++i) {
                const float rz = 1.0f / sZ[r0 + i];
                float4 o;
                o.x = accO[i][0] * rz;
                o.y = accO[i][1] * rz;
                o.z = accO[i][2] * rz;
                o.w = accO[i][3] * rz;
                *(float4*)(ob + (size_t)(t0 + r0 + i) * tstride + c0) = o;
            }
        } else if (tid < 384) {
            // waves 4-5: commit state delta
            const int u  = tid - 256;
            const int c0 = (u >> 4) << 2;
            const int d0 = (u & 15) << 2;
            #pragma unroll
            for (int i = 0; i < 4; ++i) {
                float4 s4 = *(float4*)&sSt[c0 + i][d0];
                s4.x += accB[i][0];
                s4.y += accB[i][1];
                s4.z += accB[i][2];
                s4.w += accB[i][3];
                *(float4*)&sSt[c0 + i][d0] = s4;
            }
        }
        __syncthreads();
    }
}

extern "C" void kernel_launch(void* const* d_in, const int* in_sizes, int n_in,
                              void* d_out, int out_size, void* d_ws, size_t ws_size,
                              hipStream_t stream) {
    const float* q = (const float*)d_in[0];
    const float* k = (const float*)d_in[1];
    const float* v = (const float*)d_in[2];
    float* o = (float*)d_out;
    dim3 grid(NBATCH * NHEAD * 2);   // (n,h) x m-half = 256 blocks
    linattn_fused<<<grid, NTHREADS, 0, stream>>>(q, k, v, o);
}

// Round 2
// 87.657 us; speedup vs baseline: 4.0844x; 4.0844x over previous
//
#include <hip/hip_runtime.h>
#include <math.h>

#define NBATCH 8
#define SEQL   2048
#define NHEAD  16
#define DDIM   64
#define CHK    64
#define NCHUNK (SEQL / CHK)
#define MH     32          // m-columns per block (m-split across 2 blocks)
#define NTHREADS 256
#define EPSV   1e-6f
#define LSTR   72          // bf16 row stride: 144B -> 16B-aligned, +4-bank row offset
#define KSTR   68          // sKt stride: 136B, 8B-aligned (b64 frag reads), eases scatter

typedef float f32x4  __attribute__((ext_vector_type(4)));
typedef short bf16x8 __attribute__((ext_vector_type(8)));

#define MFMA16(a, b, c) __builtin_amdgcn_mfma_f32_16x16x32_bf16((a), (b), (c), 0, 0, 0)

__device__ __forceinline__ float phi(float x) { return x > 0.0f ? x + 1.0f : __expf(x); }

__device__ __forceinline__ ushort f2bf(float x) {     // RNE bf16 (finite inputs)
    union { float f; unsigned int i; } t; t.f = x;
    unsigned int r = t.i + 0x7fffu + ((t.i >> 16) & 1u);
    return (ushort)(r >> 16);
}
__device__ __forceinline__ float bf2f(ushort u) {
    union { unsigned int i; float f; } t; t.i = ((unsigned int)u) << 16; return t.f;
}

__device__ __forceinline__ bf16x8 ld8(const ushort* p) {        // 16B-aligned
    return *reinterpret_cast<const bf16x8*>(p);
}
__device__ __forceinline__ bf16x8 ld8u(const ushort* p) {       // 8B-aligned (2x b64)
    ushort4 a = *reinterpret_cast<const ushort4*>(p);
    ushort4 b = *reinterpret_cast<const ushort4*>(p + 4);
    bf16x8 f;
    f[0] = (short)a.x; f[1] = (short)a.y; f[2] = (short)a.z; f[3] = (short)a.w;
    f[4] = (short)b.x; f[5] = (short)b.y; f[6] = (short)b.z; f[7] = (short)b.w;
    return f;
}

__global__ __launch_bounds__(NTHREADS)
void linattn_mfma(const float* __restrict__ qg, const float* __restrict__ kg,
                  const float* __restrict__ vg, float* __restrict__ og) {
    // bf16 staging (row-major [out_idx][k] for every MFMA operand)
    __shared__ ushort sQ[64][LSTR];    // phi(Q)  [t][d]
    __shared__ ushort sK[64][LSTR];    // phi(K)  [s][d]   (QK^T B-operand)
    __shared__ ushort sP[64][LSTR];    // masked P [t][s]
    __shared__ ushort sVt[MH][LSTR];   // V^T     [m][s]
    __shared__ ushort sSt[MH][LSTR];   // S_old^T [m][d]
    __shared__ ushort sKt[64][KSTR];   // phi(K)^T [d][s]  (state-update A-operand)
    __shared__ float  sKsum[64];       // running column-sum of phi(K) (prev chunks)
    __shared__ float  sRs[64];         // rowsum of masked P
    __shared__ float  sZ[64];          // normalizer
    __shared__ float  sZq[64][4];      // q . ksum_prev partials
    __shared__ float  sKs4[64][4];     // this-chunk ksum partials

    const int tid = threadIdx.x;
    const int w   = tid >> 6;          // wave 0..3 -> row strip 16w..16w+15
    const int l   = tid & 63;
    const int lr  = l & 15;            // A-row / B-col / D-col within tile
    const int lk  = l >> 4;            // k lane-group

    const int bid   = blockIdx.x;
    const int nh    = bid & 127;       // blocks b, b+128 share (n,h) -> same XCD slot
    const int mhalf = bid >> 7;
    const int n  = nh >> 4;
    const int hh = nh & 15;

    const size_t tstride = (size_t)NHEAD * DDIM;   // 1024 floats per timestep
    const size_t base0 = ((size_t)n * SEQL * NHEAD + hh) * DDIM;
    const float* qb = qg + base0;
    const float* kb = kg + base0;
    const float* vb = vg + base0 + (size_t)mhalf * MH;
    float*       ob = og + base0 + (size_t)mhalf * MH;

    // global->reg load geometry (coalesced float4)
    const int qk_row = tid >> 4;            // + 16*i
    const int qk_c4  = (tid & 15) << 2;
    const int v_row  = tid >> 3;            // + 32*i
    const int v_c4   = (tid & 7) << 2;

    float4 qr[4], kr[4], vr[2];
    #pragma unroll
    for (int i = 0; i < 4; ++i) {
        qr[i] = *(const float4*)(qb + (size_t)(qk_row + 16 * i) * tstride + qk_c4);
        kr[i] = *(const float4*)(kb + (size_t)(qk_row + 16 * i) * tstride + qk_c4);
    }
    #pragma unroll
    for (int i = 0; i < 2; ++i)
        vr[i] = *(const float4*)(vb + (size_t)(v_row + 32 * i) * tstride + v_c4);

    const f32x4 zero4 = {0.0f, 0.0f, 0.0f, 0.0f};
    f32x4 accS[2];                      // persistent state S[d][m] strip (fp32)
    accS[0] = zero4; accS[1] = zero4;
    if (tid < 64) sKsum[tid] = 0.0f;

    const int rowbase = 16 * w + 4 * lk;   // D-row base for this lane

    for (int tc = 0; tc < NCHUNK; ++tc) {
        const int t0 = tc * CHK;

        // ---------------- phase A: regs -> LDS staging ----------------
        #pragma unroll
        for (int i = 0; i < 4; ++i) {
            const int row = qk_row + 16 * i;
            const float4 q4 = qr[i], k4 = kr[i];
            ushort4 qp, kp;
            qp.x = f2bf(phi(q4.x)); qp.y = f2bf(phi(q4.y));
            qp.z = f2bf(phi(q4.z)); qp.w = f2bf(phi(q4.w));
            kp.x = f2bf(phi(k4.x)); kp.y = f2bf(phi(k4.y));
            kp.z = f2bf(phi(k4.z)); kp.w = f2bf(phi(k4.w));
            *(ushort4*)&sQ[row][qk_c4] = qp;
            *(ushort4*)&sK[row][qk_c4] = kp;
            sKt[qk_c4 + 0][row] = kp.x; sKt[qk_c4 + 1][row] = kp.y;
            sKt[qk_c4 + 2][row] = kp.z; sKt[qk_c4 + 3][row] = kp.w;
        }
        #pragma unroll
        for (int i = 0; i < 2; ++i) {
            const int row = v_row + 32 * i;
            const float4 v4 = vr[i];
            sVt[v_c4 + 0][row] = f2bf(v4.x); sVt[v_c4 + 1][row] = f2bf(v4.y);
            sVt[v_c4 + 2][row] = f2bf(v4.z); sVt[v_c4 + 3][row] = f2bf(v4.w);
        }
        // snapshot S_old -> sSt[m][d] (bf16)
        #pragma unroll
        for (int c = 0; c < 2; ++c)
            #pragma unroll
            for (int r = 0; r < 4; ++r)
                sSt[16 * c + lr][rowbase + r] = f2bf(accS[c][r]);
        __syncthreads();

        // ---------------- phase B: prefetch + QK^T + QS + qz ----------
        if (tc + 1 < NCHUNK) {
            const int t1 = t0 + CHK;
            #pragma unroll
            for (int i = 0; i < 4; ++i) {
                qr[i] = *(const float4*)(qb + (size_t)(t1 + qk_row + 16 * i) * tstride + qk_c4);
                kr[i] = *(const float4*)(kb + (size_t)(t1 + qk_row + 16 * i) * tstride + qk_c4);
            }
            #pragma unroll
            for (int i = 0; i < 2; ++i)
                vr[i] = *(const float4*)(vb + (size_t)(t1 + v_row + 32 * i) * tstride + v_c4);
        }

        const ushort* qrow = &sQ[16 * w + lr][0];
        const bf16x8 aQ0 = ld8(qrow + 8 * lk);
        const bf16x8 aQ1 = ld8(qrow + 32 + 8 * lk);

        f32x4 accP[4];
        #pragma unroll
        for (int c = 0; c < 4; ++c) {
            accP[c] = zero4;
            const ushort* krow = &sK[16 * c + lr][0];
            accP[c] = MFMA16(aQ0, ld8(krow + 8 * lk), accP[c]);
            accP[c] = MFMA16(aQ1, ld8(krow + 32 + 8 * lk), accP[c]);
        }
        // causal mask + rowsum (D: row = rowbase+r, col = 16c+lr)
        float rsum[4] = {0.0f, 0.0f, 0.0f, 0.0f};
        #pragma unroll
        for (int c = 0; c < 4; ++c) {
            const int col = 16 * c + lr;
            #pragma unroll
            for (int r = 0; r < 4; ++r) {
                const float pv = (col <= rowbase + r) ? accP[c][r] : 0.0f;
                accP[c][r] = pv;
                rsum[r] += pv;
            }
        }
        #pragma unroll
        for (int r = 0; r < 4; ++r) {
            rsum[r] += __shfl_xor(rsum[r], 1);
            rsum[r] += __shfl_xor(rsum[r], 2);
            rsum[r] += __shfl_xor(rsum[r], 4);
            rsum[r] += __shfl_xor(rsum[r], 8);
        }
        if (lr == 0) {
            #pragma unroll
            for (int r = 0; r < 4; ++r) sRs[rowbase + r] = rsum[r];
        }
        // write masked P (bf16)
        #pragma unroll
        for (int c = 0; c < 4; ++c)
            #pragma unroll
            for (int r = 0; r < 4; ++r)
                sP[rowbase + r][16 * c + lr] = f2bf(accP[c][r]);
        // O_inter = Q . S_old
        f32x4 accO[2];
        #pragma unroll
        for (int c2 = 0; c2 < 2; ++c2) {
            accO[c2] = zero4;
            const ushort* srow = &sSt[16 * c2 + lr][0];
            accO[c2] = MFMA16(aQ0, ld8(srow + 8 * lk), accO[c2]);
            accO[c2] = MFMA16(aQ1, ld8(srow + 32 + 8 * lk), accO[c2]);
        }
        // qz partial: q_row . ksum_prev
        {
            const int row = tid >> 2, qq = tid & 3;
            const ushort* q2 = &sQ[row][16 * qq];
            const float* ks  = &sKsum[16 * qq];
            float zp = 0.0f;
            #pragma unroll
            for (int j4 = 0; j4 < 4; ++j4) {
                const ushort4 u = *(const ushort4*)(q2 + 4 * j4);
                zp += bf2f(u.x) * ks[4 * j4 + 0] + bf2f(u.y) * ks[4 * j4 + 1]
                    + bf2f(u.z) * ks[4 * j4 + 2] + bf2f(u.w) * ks[4 * j4 + 3];
            }
            sZq[row][qq] = zp;
        }
        __syncthreads();

        // ---------------- phase C: PV + KtV + z finalize ----------------
        const ushort* prow = &sP[16 * w + lr][0];
        const ushort* ktr  = &sKt[16 * w + lr][0];
        #pragma unroll
        for (int ks = 0; ks < 2; ++ks) {
            const bf16x8 aP = ld8(prow + 32 * ks + 8 * lk);
            const bf16x8 aK = ld8u(ktr + 32 * ks + 8 * lk);
            #pragma unroll
            for (int c2 = 0; c2 < 2; ++c2) {
                const bf16x8 bV = ld8(&sVt[16 * c2 + lr][32 * ks + 8 * lk]);
                accO[c2] = MFMA16(aP, bV, accO[c2]);   // intra-chunk
                accS[c2] = MFMA16(aK, bV, accS[c2]);   // state += K^T V
            }
        }
        if (tid < 64)
            sZ[tid] = sRs[tid] + sZq[tid][0] + sZq[tid][1] + sZq[tid][2] + sZq[tid][3] + EPSV;
        {   // this-chunk k column-sum partials
            const int dd = tid >> 2, qq = tid & 3;
            const ushort* k2 = &sKt[dd][16 * qq];
            float kp = 0.0f;
            #pragma unroll
            for (int j4 = 0; j4 < 4; ++j4) {
                const ushort4 u = *(const ushort4*)(k2 + 4 * j4);
                kp += bf2f(u.x) + bf2f(u.y) + bf2f(u.z) + bf2f(u.w);
            }
            sKs4[dd][qq] = kp;
        }
        __syncthreads();

        // ---------------- phase D: normalize + store; ksum commit -------
        if (tid < 64)
            sKsum[tid] += sKs4[tid][0] + sKs4[tid][1] + sKs4[tid][2] + sKs4[tid][3];
        #pragma unroll
        for (int r = 0; r < 4; ++r) {
            const int trow = rowbase + r;
            const float rz = 1.0f / sZ[trow];
            #pragma unroll
            for (int c2 = 0; c2 < 2; ++c2)
                ob[(size_t)(t0 + trow) * tstride + 16 * c2 + lr] = accO[c2][r] * rz;
        }
        // no barrier needed: next phase-A writes touch arrays fully consumed
        // before the C->D barrier; sKsum/sZ cross-phase reads are barrier-ordered.
    }
}

extern "C" void kernel_launch(void* const* d_in, const int* in_sizes, int n_in,
                              void* d_out, int out_size, void* d_ws, size_t ws_size,
                              hipStream_t stream) {
    const float* q = (const float*)d_in[0];
    const float* k = (const float*)d_in[1];
    const float* v = (const float*)d_in[2];
    float* o = (float*)d_out;
    dim3 grid(NBATCH * NHEAD * 2);   // 128 (n,h) x 2 m-halves = 256 blocks
    linattn_mfma<<<grid, NTHREADS, 0, stream>>>(q, k, v, o);
}

// Round 3
// 81.731 us; speedup vs baseline: 4.3806x; 1.0725x over previous
//
#include <hip/hip_runtime.h>
#include <math.h>

#define NBATCH 8
#define SEQL   2048
#define NHEAD  16
#define DDIM   64
#define CHK    128
#define NCHUNK (SEQL / CHK)
#define MH     32          // m-columns per block (m-split across 2 blocks)
#define NTHREADS 512
#define EPSV   1e-6f
#define QSTR   72          // sQ/sK/sSt row stride: 144B, 16B-aligned
#define PSTR   132         // sP row stride: 264B, 8B-aligned, full bank spread on scatter
#define KTSTR  66          // sKt (half) row stride: 132B, 4B-aligned, 4-way scatter
#define VSTR   132         // sVt row stride: 264B, 8B-aligned, 4-way scatter

typedef float f32x4  __attribute__((ext_vector_type(4)));
typedef short bf16x8 __attribute__((ext_vector_type(8)));

#define MFMA16(a,b,c) __builtin_amdgcn_mfma_f32_16x16x32_bf16((a),(b),(c),0,0,0)

__device__ __forceinline__ float phi(float x) { return x > 0.0f ? x + 1.0f : __expf(x); }

__device__ __forceinline__ ushort f2bf(float x) {     // RNE bf16 (finite inputs)
    union { float f; unsigned int i; } t; t.f = x;
    unsigned int r = t.i + 0x7fffu + ((t.i >> 16) & 1u);
    return (ushort)(r >> 16);
}
__device__ __forceinline__ float bf2f(ushort u) {
    union { unsigned int i; float f; } t; t.i = ((unsigned int)u) << 16; return t.f;
}

// LDS fragment loads at different guaranteed alignments
__device__ __forceinline__ bf16x8 ld16B(const ushort* p) {    // 16B-aligned
    return *reinterpret_cast<const bf16x8*>(p);
}
__device__ __forceinline__ bf16x8 ld8B(const ushort* p) {     // 8B-aligned
    union { bf16x8 v; uint2 u[2]; } x;
    x.u[0] = *(const uint2*)p;
    x.u[1] = *(const uint2*)(p + 4);
    return x.v;
}
__device__ __forceinline__ bf16x8 ld4B(const ushort* p) {     // 4B-aligned
    union { bf16x8 v; unsigned int u[4]; } x;
    const unsigned int* q = (const unsigned int*)p;
    x.u[0] = q[0]; x.u[1] = q[1]; x.u[2] = q[2]; x.u[3] = q[3];
    return x.v;
}

__global__ __launch_bounds__(NTHREADS, 2)
void linattn_mfma2(const float* __restrict__ qg, const float* __restrict__ kg,
                   const float* __restrict__ vg, float* __restrict__ og) {
    __shared__ __align__(16) ushort sQ[CHK][QSTR];     // phi(Q) [t][d]
    __shared__ __align__(16) ushort sK[CHK][QSTR];     // phi(K) [s][d]
    __shared__ __align__(16) ushort sP[CHK][PSTR];     // masked P [t][s]
    __shared__ __align__(16) ushort sKtA[DDIM][KTSTR]; // phi(K)^T [d][s], s=0..63
    __shared__ __align__(16) ushort sKtB[DDIM][KTSTR]; // phi(K)^T [d][s], s=64..127
    __shared__ __align__(16) ushort sVt[MH][VSTR];     // V^T [m][s]
    __shared__ __align__(16) ushort sStA[MH][QSTR];    // S snapshot (k-half A) [m][d]
    __shared__ __align__(16) ushort sStB[MH][QSTR];    // S snapshot (k-half B) [m][d]
    __shared__ float sKsW[2][8][64];                   // per-wave colsum partials (ping-pong)
    __shared__ float sKS[2][64];                       // running ksum (ping-pong)

    const int tid = threadIdx.x;
    const int w   = tid >> 6;          // wave 0..7 -> P/O row strip 16w..16w+15
    const int l   = tid & 63;
    const int lr  = l & 15;
    const int lk  = l >> 4;
    const int sw  = w & 3;             // state d-strip
    const int kh  = w >> 2;            // state k-half (s 0..63 / 64..127)

    const int bid   = blockIdx.x;
    const int nh    = bid & 127;       // blocks b, b+128 share (n,h) -> same XCD slot
    const int mhalf = bid >> 7;
    const int n  = nh >> 4;
    const int hh = nh & 15;

    const size_t tstride = (size_t)NHEAD * DDIM;       // 1024 floats per timestep
    const size_t base0 = ((size_t)n * SEQL * NHEAD + hh) * DDIM;
    const float* qb = qg + base0;
    const float* kb = kg + base0;
    const float* vb = vg + base0 + (size_t)mhalf * MH;
    float*       ob = og + base0 + (size_t)mhalf * MH;

    // global->reg load geometry (coalesced float4)
    const int qk_row = tid >> 4;           // + 32*i, i=0..3
    const int qk_c4  = (tid & 15) << 2;
    const int v_row  = tid >> 3;           // + 64*i, i=0..1
    const int v_c4   = (tid & 7) << 2;

    float4 qr[4], kr[4], vr[2];
    #pragma unroll
    for (int i = 0; i < 4; ++i) {
        qr[i] = *(const float4*)(qb + (size_t)(qk_row + 32 * i) * tstride + qk_c4);
        kr[i] = *(const float4*)(kb + (size_t)(qk_row + 32 * i) * tstride + qk_c4);
    }
    #pragma unroll
    for (int i = 0; i < 2; ++i)
        vr[i] = *(const float4*)(vb + (size_t)(v_row + 64 * i) * tstride + v_c4);

    if (tid < 64) sKS[0][tid] = 0.0f;

    const f32x4 zero4 = {0.0f, 0.0f, 0.0f, 0.0f};
    f32x4 accS[2];                     // persistent state half-strip (fp32)
    accS[0] = zero4; accS[1] = zero4;

    const int rowbase = 16 * w + 4 * lk;   // D-row base (row = rowbase + reg)

    for (int tc = 0; tc < NCHUNK; ++tc) {
        const int t0 = tc * CHK;
        const int cur = tc & 1, prv = cur ^ 1;

        // ================= phase A: commit ksum; stage chunk =================
        if (tc > 0 && tid < 64) {
            float s = sKS[prv][tid];
            #pragma unroll
            for (int ww = 0; ww < 8; ++ww) s += sKsW[prv][ww][tid];
            sKS[cur][tid] = s;
        }
        float kpart[4] = {0.0f, 0.0f, 0.0f, 0.0f};
        #pragma unroll
        for (int i = 0; i < 4; ++i) {
            const int row = qk_row + 32 * i;
            const float4 q4 = qr[i], k4 = kr[i];
            const float kx = phi(k4.x), ky = phi(k4.y), kz = phi(k4.z), kw = phi(k4.w);
            kpart[0] += kx; kpart[1] += ky; kpart[2] += kz; kpart[3] += kw;
            ushort4 qp, kp;
            qp.x = f2bf(phi(q4.x)); qp.y = f2bf(phi(q4.y));
            qp.z = f2bf(phi(q4.z)); qp.w = f2bf(phi(q4.w));
            kp.x = f2bf(kx); kp.y = f2bf(ky); kp.z = f2bf(kz); kp.w = f2bf(kw);
            *(ushort4*)&sQ[row][qk_c4] = qp;
            *(ushort4*)&sK[row][qk_c4] = kp;
            ushort* kt = (row < 64) ? &sKtA[0][0] : &sKtB[0][0];
            const int sp = row & 63;
            kt[(qk_c4 + 0) * KTSTR + sp] = kp.x;
            kt[(qk_c4 + 1) * KTSTR + sp] = kp.y;
            kt[(qk_c4 + 2) * KTSTR + sp] = kp.z;
            kt[(qk_c4 + 3) * KTSTR + sp] = kp.w;
        }
        #pragma unroll
        for (int j = 0; j < 4; ++j) {    // reduce colsum over this wave's 4 rows x 4 i
            kpart[j] += __shfl_xor(kpart[j], 16);
            kpart[j] += __shfl_xor(kpart[j], 32);
        }
        if (l < 16) *(float4*)&sKsW[cur][w][4 * l] = *(float4*)kpart;
        #pragma unroll
        for (int i = 0; i < 2; ++i) {
            const int row = v_row + 64 * i;
            const float4 v4 = vr[i];
            sVt[v_c4 + 0][row] = f2bf(v4.x);
            sVt[v_c4 + 1][row] = f2bf(v4.y);
            sVt[v_c4 + 2][row] = f2bf(v4.z);
            sVt[v_c4 + 3][row] = f2bf(v4.w);
        }
        {   // snapshot S (this wave's k-half) -> sSt{A,B}[m][d], vectorized
            ushort* st = (kh == 0) ? &sStA[0][0] : &sStB[0][0];
            #pragma unroll
            for (int c2 = 0; c2 < 2; ++c2) {
                ushort4 s4;
                s4.x = f2bf(accS[c2][0]); s4.y = f2bf(accS[c2][1]);
                s4.z = f2bf(accS[c2][2]); s4.w = f2bf(accS[c2][3]);
                *(ushort4*)(st + (16 * c2 + lr) * QSTR + 16 * sw + 4 * lk) = s4;
            }
        }
        __syncthreads();   // bar1: staging visible

        // ================= phase B: prefetch; QK^T; QS; z =================
        if (tc + 1 < NCHUNK) {
            const int t1 = t0 + CHK;
            #pragma unroll
            for (int i = 0; i < 4; ++i) {
                qr[i] = *(const float4*)(qb + (size_t)(t1 + qk_row + 32 * i) * tstride + qk_c4);
                kr[i] = *(const float4*)(kb + (size_t)(t1 + qk_row + 32 * i) * tstride + qk_c4);
            }
            #pragma unroll
            for (int i = 0; i < 2; ++i)
                vr[i] = *(const float4*)(vb + (size_t)(t1 + v_row + 64 * i) * tstride + v_c4);
        }

        const ushort* qrow = &sQ[16 * w + lr][0];
        const bf16x8 aQ0 = ld16B(qrow + 8 * lk);
        const bf16x8 aQ1 = ld16B(qrow + 32 + 8 * lk);

        f32x4 accP[8];
        #pragma unroll
        for (int c = 0; c < 8; ++c) {
            accP[c] = zero4;
            const ushort* krow = &sK[16 * c + lr][0];
            accP[c] = MFMA16(aQ0, ld16B(krow + 8 * lk), accP[c]);
            accP[c] = MFMA16(aQ1, ld16B(krow + 32 + 8 * lk), accP[c]);
        }
        // causal mask + in-register rowsum
        float rsum[4] = {0.0f, 0.0f, 0.0f, 0.0f};
        #pragma unroll
        for (int c = 0; c < 8; ++c) {
            const int col = 16 * c + lr;
            #pragma unroll
            for (int r = 0; r < 4; ++r) {
                const float pv = (col <= rowbase + r) ? accP[c][r] : 0.0f;
                accP[c][r] = pv;
                rsum[r] += pv;
            }
        }
        #pragma unroll
        for (int r = 0; r < 4; ++r) {
            rsum[r] += __shfl_xor(rsum[r], 1);
            rsum[r] += __shfl_xor(rsum[r], 2);
            rsum[r] += __shfl_xor(rsum[r], 4);
            rsum[r] += __shfl_xor(rsum[r], 8);
        }
        // write masked P (same-wave consumer; no barrier needed)
        #pragma unroll
        for (int c = 0; c < 8; ++c)
            #pragma unroll
            for (int r = 0; r < 4; ++r)
                sP[rowbase + r][16 * c + lr] = f2bf(accP[c][r]);
        // O_inter = Q . (S_A + S_B)
        f32x4 accO[2];
        #pragma unroll
        for (int c2 = 0; c2 < 2; ++c2) {
            accO[c2] = zero4;
            const ushort* sa = &sStA[16 * c2 + lr][0];
            const ushort* sb = &sStB[16 * c2 + lr][0];
            accO[c2] = MFMA16(aQ0, ld16B(sa + 8 * lk), accO[c2]);
            accO[c2] = MFMA16(aQ1, ld16B(sa + 32 + 8 * lk), accO[c2]);
            accO[c2] = MFMA16(aQ0, ld16B(sb + 8 * lk), accO[c2]);
            accO[c2] = MFMA16(aQ1, ld16B(sb + 32 + 8 * lk), accO[c2]);
        }
        // qz: row 16w+lr, d-range 16lk..16lk+15; then wave-combine
        float zp = 0.0f;
        {
            const ushort* q2 = &sQ[16 * w + lr][16 * lk];
            const float*  ks = &sKS[cur][16 * lk];
            #pragma unroll
            for (int j4 = 0; j4 < 4; ++j4) {
                const ushort4 u = *(const ushort4*)(q2 + 4 * j4);
                zp += bf2f(u.x) * ks[4 * j4 + 0] + bf2f(u.y) * ks[4 * j4 + 1]
                    + bf2f(u.z) * ks[4 * j4 + 2] + bf2f(u.w) * ks[4 * j4 + 3];
            }
        }
        zp += __shfl_xor(zp, 16);
        zp += __shfl_xor(zp, 32);          // all lanes: full qz for row 16w+lr
        float zinv[4];
        #pragma unroll
        for (int r = 0; r < 4; ++r)
            zinv[r] = 1.0f / (rsum[r] + __shfl(zp, 4 * lk + r) + EPSV);

        // ================= phase C: PV; state update; store (no barrier before) =====
        const ushort* prow = &sP[16 * w + lr][0];
        #pragma unroll
        for (int ks = 0; ks < 4; ++ks) {
            const bf16x8 aP = ld8B(prow + 32 * ks + 8 * lk);
            #pragma unroll
            for (int c2 = 0; c2 < 2; ++c2) {
                const bf16x8 bV = ld8B(&sVt[16 * c2 + lr][32 * ks + 8 * lk]);
                accO[c2] = MFMA16(aP, bV, accO[c2]);
            }
        }
        const ushort* ktrow = (kh == 0) ? &sKtA[16 * sw + lr][0] : &sKtB[16 * sw + lr][0];
        #pragma unroll
        for (int ks2 = 0; ks2 < 2; ++ks2) {
            const bf16x8 aK = ld4B(ktrow + 32 * ks2 + 8 * lk);
            #pragma unroll
            for (int c2 = 0; c2 < 2; ++c2) {
                const bf16x8 bV = ld8B(&sVt[16 * c2 + lr][64 * kh + 32 * ks2 + 8 * lk]);
                accS[c2] = MFMA16(aK, bV, accS[c2]);
            }
        }
        #pragma unroll
        for (int r = 0; r < 4; ++r) {
            const int trow = rowbase + r;
            #pragma unroll
            for (int c2 = 0; c2 < 2; ++c2)
                ob[(size_t)(t0 + trow) * tstride + 16 * c2 + lr] = accO[c2][r] * zinv[r];
        }
        __syncthreads();   // bar2: LDS consumed, safe to restage
    }
}

extern "C" void kernel_launch(void* const* d_in, const int* in_sizes, int n_in,
                              void* d_out, int out_size, void* d_ws, size_t ws_size,
                              hipStream_t stream) {
    const float* q = (const float*)d_in[0];
    const float* k = (const float*)d_in[1];
    const float* v = (const float*)d_in[2];
    float* o = (float*)d_out;
    dim3 grid(NBATCH * NHEAD * 2);   // 128 (n,h) x 2 m-halves = 256 blocks
    linattn_mfma2<<<grid, NTHREADS, 0, stream>>>(q, k, v, o);
}

// Round 4
// 62.875 us; speedup vs baseline: 5.6942x; 1.2999x over previous
//
#include <hip/hip_runtime.h>
#include <math.h>

#define NBATCH 8
#define SEQL   2048
#define NHEAD  16
#define DDIM   64
#define CHK    128
#define NCHUNK (SEQL / CHK)
#define MH     32          // m-columns per block (m-split across 2 blocks)
#define NTHREADS 1024
#define EPSV   1e-6f
#define QSTR   72          // sQ/sK/sSt row stride (ushorts): 144B, 16B-aligned
#define PSTR   132         // sP row stride: 264B, 8B-aligned, conflict-free scatter
#define KTSTR  66          // sKt half row stride: 132B, 4B-aligned
#define VSTR   132         // sVt row stride: 264B

typedef float f32x4  __attribute__((ext_vector_type(4)));
typedef short bf16x8 __attribute__((ext_vector_type(8)));

#define MFMA16(a,b,c) __builtin_amdgcn_mfma_f32_16x16x32_bf16((a),(b),(c),0,0,0)

__device__ __forceinline__ float phi(float x) { return x > 0.0f ? x + 1.0f : __expf(x); }

__device__ __forceinline__ unsigned int cvt_pk(float lo, float hi) {  // 2xf32 -> packed bf16 (RNE)
    unsigned int r;
    asm("v_cvt_pk_bf16_f32 %0, %1, %2" : "=v"(r) : "v"(lo), "v"(hi));
    return r;
}
__device__ __forceinline__ ushort f2bf(float x) {                    // scalar RNE
    union { float f; unsigned int i; } t; t.f = x;
    unsigned int r = t.i + 0x7fffu + ((t.i >> 16) & 1u);
    return (ushort)(r >> 16);
}

__device__ __forceinline__ bf16x8 ld16B(const ushort* p) {
    return *reinterpret_cast<const bf16x8*>(p);
}
__device__ __forceinline__ bf16x8 ld8B(const ushort* p) {
    union { bf16x8 v; uint2 u[2]; } x;
    x.u[0] = *(const uint2*)p;
    x.u[1] = *(const uint2*)(p + 4);
    return x.v;
}
__device__ __forceinline__ bf16x8 ld4B(const ushort* p) {
    union { bf16x8 v; unsigned int u[4]; } x;
    const unsigned int* q = (const unsigned int*)p;
    x.u[0] = q[0]; x.u[1] = q[1]; x.u[2] = q[2]; x.u[3] = q[3];
    return x.v;
}

__global__ __launch_bounds__(NTHREADS)
void linattn_mfma3(const float* __restrict__ qg, const float* __restrict__ kg,
                   const float* __restrict__ vg, float* __restrict__ og) {
    __shared__ __align__(16) ushort sQ[CHK][QSTR];        // phi(Q) [t][d]
    __shared__ __align__(16) ushort sK[CHK][QSTR];        // phi(K) [s][d]
    __shared__ __align__(16) ushort sP[CHK][PSTR];        // masked P [t][s] (upper tri stays 0)
    __shared__ __align__(16) ushort sKt[2][2][DDIM][KTSTR]; // phi(K)^T [pp][s-half][d][s']
    __shared__ __align__(16) ushort sVt[2][MH][VSTR];     // V^T [pp][m][s]
    __shared__ __align__(16) ushort sStA[MH][QSTR];       // S_prev snapshot, k-half A [m][d]
    __shared__ __align__(16) ushort sStB[MH][QSTR];       // S_prev snapshot, k-half B [m][d]
    __shared__ float sKsW[2][16][64];                     // per-wave colsum partials (pp)
    __shared__ float sKS[64];                             // running ksum (prev chunks, f32)
    __shared__ __align__(16) ushort sKSbf[64];            // ksum as bf16 row (z-MFMA B-op)

    const int tid = threadIdx.x;
    const int w   = tid >> 6;           // wave 0..15
    const int l   = tid & 63;
    const int lr  = l & 15;
    const int lk  = l >> 4;
    const int R   = w >> 1;             // output/P row-strip (16 rows)
    const int M2  = w & 1;              // m-tile (and QK^T col-group)
    const int t8  = w & 7;              // state tile id
    const int D4  = t8 >> 1;            // state d-tile
    const int SM2 = t8 & 1;             // state m-tile
    const int kh  = w >> 3;             // state k-half (s 0..63 / 64..127)

    const int bid   = blockIdx.x;
    const int nh    = bid & 127;        // b and b+128 share (n,h) -> same XCD slot
    const int mhalf = bid >> 7;
    const int n  = nh >> 4;
    const int hh = nh & 15;

    const size_t tstride = (size_t)NHEAD * DDIM;
    const size_t base0 = ((size_t)n * SEQL * NHEAD + hh) * DDIM;
    const float* qb = qg + base0;
    const float* kb = kg + base0;
    const float* vb = vg + base0 + (size_t)mhalf * MH;
    float*       ob = og + base0 + (size_t)mhalf * MH;

    // global load geometry
    const int qk_row = tid >> 4;            // + 64*i
    const int qk_c4  = (tid & 15) << 2;
    const int v_row  = tid >> 3;            // exactly 128 rows
    const int v_c4   = (tid & 7) << 2;

    float4 qr[2], kr[2], vr;
    #pragma unroll
    for (int i = 0; i < 2; ++i) {
        qr[i] = *(const float4*)(qb + (size_t)(qk_row + 64 * i) * tstride + qk_c4);
        kr[i] = *(const float4*)(kb + (size_t)(qk_row + 64 * i) * tstride + qk_c4);
    }
    vr = *(const float4*)(vb + (size_t)v_row * tstride + v_c4);

    // pre-zero sP (upper triangle stays zero forever) and init ksum
    for (int i = tid; i < CHK * PSTR / 2; i += NTHREADS)
        ((unsigned int*)&sP[0][0])[i] = 0u;
    if (tid < 64) sKS[tid] = 0.0f;

    const f32x4 zero4 = {0.0f, 0.0f, 0.0f, 0.0f};
    f32x4 accS = zero4;                 // persistent state tile (fp32, this wave's slice)
    bf16x8 ones;
    #pragma unroll
    for (int j = 0; j < 8; ++j) ones[j] = (short)0x3F80;   // bf16 1.0

    const int rowb = 16 * R + 4 * lk;   // D rows of this lane: rowb + r

    for (int tc = 0; tc < NCHUNK; ++tc) {
        const int t0 = tc * CHK;
        const int cur = tc & 1, prv = cur ^ 1;

        // ============ phase A: commit ksum; stage chunk ============
        if (tid < 64) {
            float s = sKS[tid];
            if (tc > 0) {
                #pragma unroll
                for (int ww = 0; ww < 16; ++ww) s += sKsW[prv][ww][tid];
                sKS[tid] = s;
            }
            sKSbf[tid] = f2bf(s);
        }
        float kpart[4] = {0.0f, 0.0f, 0.0f, 0.0f};
        #pragma unroll
        for (int i = 0; i < 2; ++i) {
            const int row = qk_row + 64 * i;
            const float4 q4 = qr[i], k4 = kr[i];
            const float kx = phi(k4.x), ky = phi(k4.y), kz = phi(k4.z), kw = phi(k4.w);
            kpart[0] += kx; kpart[1] += ky; kpart[2] += kz; kpart[3] += kw;
            uint2 qp, kp;
            qp.x = cvt_pk(phi(q4.x), phi(q4.y));
            qp.y = cvt_pk(phi(q4.z), phi(q4.w));
            kp.x = cvt_pk(kx, ky);
            kp.y = cvt_pk(kz, kw);
            *(uint2*)&sQ[row][qk_c4] = qp;
            *(uint2*)&sK[row][qk_c4] = kp;
            ushort* kt = &sKt[cur][i][0][0];
            const int sp = row & 63;
            kt[(qk_c4 + 0) * KTSTR + sp] = (ushort)kp.x;
            kt[(qk_c4 + 1) * KTSTR + sp] = (ushort)(kp.x >> 16);
            kt[(qk_c4 + 2) * KTSTR + sp] = (ushort)kp.y;
            kt[(qk_c4 + 3) * KTSTR + sp] = (ushort)(kp.y >> 16);
        }
        #pragma unroll
        for (int j = 0; j < 4; ++j) {
            kpart[j] += __shfl_xor(kpart[j], 16);
            kpart[j] += __shfl_xor(kpart[j], 32);
        }
        if (l < 16) *(float4*)&sKsW[cur][w][4 * l] = *(float4*)kpart;
        {
            const unsigned int p0 = cvt_pk(vr.x, vr.y), p1 = cvt_pk(vr.z, vr.w);
            sVt[cur][v_c4 + 0][v_row] = (ushort)p0;
            sVt[cur][v_c4 + 1][v_row] = (ushort)(p0 >> 16);
            sVt[cur][v_c4 + 2][v_row] = (ushort)p1;
            sVt[cur][v_c4 + 3][v_row] = (ushort)(p1 >> 16);
        }
        {   // snapshot S_prev (this wave's tile, its k-half buffer)
            ushort* st = (kh == 0) ? &sStA[0][0] : &sStB[0][0];
            uint2 s2;
            s2.x = cvt_pk(accS[0], accS[1]);
            s2.y = cvt_pk(accS[2], accS[3]);
            *(uint2*)(st + (16 * SM2 + lr) * QSTR + 16 * D4 + 4 * lk) = s2;
        }
        __syncthreads();   // bar1

        // ============ phase B: prefetch; QK^T(+skip); QS; z-MFMA ============
        if (tc + 1 < NCHUNK) {
            const int t1 = t0 + CHK;
            #pragma unroll
            for (int i = 0; i < 2; ++i) {
                qr[i] = *(const float4*)(qb + (size_t)(t1 + qk_row + 64 * i) * tstride + qk_c4);
                kr[i] = *(const float4*)(kb + (size_t)(t1 + qk_row + 64 * i) * tstride + qk_c4);
            }
            vr = *(const float4*)(vb + (size_t)(t1 + v_row) * tstride + v_c4);
        }

        const ushort* qrow = &sQ[16 * R + lr][0];
        const bf16x8 aQ0 = ld16B(qrow + 8 * lk);
        const bf16x8 aQ1 = ld16B(qrow + 32 + 8 * lk);

        // z accumulator: qz via broadcast-ksum B-operand
        f32x4 accZ = zero4;
        accZ = MFMA16(aQ0, ld16B(&sKSbf[8 * lk]), accZ);
        accZ = MFMA16(aQ1, ld16B(&sKSbf[32 + 8 * lk]), accZ);

        // O_inter = Q . (S_A + S_B)
        f32x4 accO = zero4;
        {
            const ushort* sa = &sStA[16 * M2 + lr][0];
            const ushort* sb = &sStB[16 * M2 + lr][0];
            accO = MFMA16(aQ0, ld16B(sa + 8 * lk), accO);
            accO = MFMA16(aQ1, ld16B(sa + 32 + 8 * lk), accO);
            accO = MFMA16(aQ0, ld16B(sb + 8 * lk), accO);
            accO = MFMA16(aQ1, ld16B(sb + 32 + 8 * lk), accO);
        }

        // QK^T: only tiles with C4 <= R (others stay zero in sP)
        #pragma unroll
        for (int ci = 0; ci < 4; ++ci) {
            const int C4 = 4 * M2 + ci;
            if (C4 > R) continue;                       // wave-uniform skip
            const ushort* krow = &sK[16 * C4 + lr][0];
            f32x4 acc = zero4;
            acc = MFMA16(aQ0, ld16B(krow + 8 * lk), acc);
            acc = MFMA16(aQ1, ld16B(krow + 32 + 8 * lk), acc);
            if (C4 == R) {                              // diagonal tile: mask
                #pragma unroll
                for (int r = 0; r < 4; ++r)
                    acc[r] = (lr <= 4 * lk + r) ? acc[r] : 0.0f;
            }
            const unsigned int p01 = cvt_pk(acc[0], acc[1]);
            const unsigned int p23 = cvt_pk(acc[2], acc[3]);
            const int col = 16 * C4 + lr;
            sP[rowb + 0][col] = (ushort)p01;
            sP[rowb + 1][col] = (ushort)(p01 >> 16);
            sP[rowb + 2][col] = (ushort)p23;
            sP[rowb + 3][col] = (ushort)(p23 >> 16);
        }
        __syncthreads();   // bar2

        // ============ phase C: PV + rowsum-MFMA; state; store ============
        const ushort* prow = &sP[16 * R + lr][0];
        const ushort* vrow = &sVt[cur][16 * M2 + lr][0];
        #pragma unroll
        for (int ks = 0; ks < 4; ++ks) {
            const bf16x8 aP = ld8B(prow + 32 * ks + 8 * lk);
            accO = MFMA16(aP, ld8B(vrow + 32 * ks + 8 * lk), accO);
            accZ = MFMA16(aP, ones, accZ);              // rowsum(masked P)
        }
        {
            const ushort* ktr = &sKt[cur][kh][16 * D4 + lr][0];
            const ushort* vsr = &sVt[cur][16 * SM2 + lr][64 * kh];
            #pragma unroll
            for (int ks2 = 0; ks2 < 2; ++ks2) {
                const bf16x8 aK  = ld4B(ktr + 32 * ks2 + 8 * lk);
                const bf16x8 bVs = ld8B(vsr + 32 * ks2 + 8 * lk);
                accS = MFMA16(aK, bVs, accS);
            }
        }
        #pragma unroll
        for (int r = 0; r < 4; ++r) {
            const float zin = __builtin_amdgcn_rcpf(accZ[r] + EPSV);
            ob[(size_t)(t0 + rowb + r) * tstride + 16 * M2 + lr] = accO[r] * zin;
        }
        // no end barrier: bar1(t+1) orders restaging; phase-C-read buffers
        // (sVt/sKt) are ping-ponged; sP rewritten only after bar1(t+1).
    }
}

extern "C" void kernel_launch(void* const* d_in, const int* in_sizes, int n_in,
                              void* d_out, int out_size, void* d_ws, size_t ws_size,
                              hipStream_t stream) {
    const float* q = (const float*)d_in[0];
    const float* k = (const float*)d_in[1];
    const float* v = (const float*)d_in[2];
    float* o = (float*)d_out;
    dim3 grid(NBATCH * NHEAD * 2);   // 128 (n,h) x 2 m-halves = 256 blocks (1/CU)
    linattn_mfma3<<<grid, NTHREADS, 0, stream>>>(q, k, v, o);
}